// Round 8
// baseline (3208.733 us; speedup 1.0000x reference)
//
#include <hip/hip_runtime.h>

#define NB 16
#define NN 2048
#define G  64                 // blocks per batch; block owns 32 rows (4 waves x 8 rows)
#define ITERS 100

typedef float v2f __attribute__((ext_vector_type(2)));

static constexpr float INV_N = 1.0f / (float)NN;
static constexpr float NEG_INV_EPS = -10.0f;     // -1/eps, eps = 0.1

__device__ __forceinline__ float fastrcp(float x) { return __builtin_amdgcn_rcpf(x); }

// decode 4 packed fp8-e4m3 bytes -> 4 floats (HW v_cvt_pk_f32_fp8)
__device__ __forceinline__ void dec4(unsigned int u, float& f0, float& f1, float& f2, float& f3) {
    v2f lo = __builtin_amdgcn_cvt_pk_f32_fp8((int)u, false);
    v2f hi = __builtin_amdgcn_cvt_pk_f32_fp8((int)u, true);
    f0 = lo[0]; f1 = lo[1]; f2 = hi[0]; f3 = hi[1];
}

// ------------------------------------------------- build K8 = fp8(K * s_row), INVS = 1/s_row (pow2)
__global__ __launch_bounds__(256) void build_K(const float* __restrict__ x,
                                               const float* __restrict__ y,
                                               unsigned char* __restrict__ K8,
                                               float* __restrict__ INVS) {
    const int n = blockIdx.x, b = blockIdx.y, tid = threadIdx.x;
    const int w = tid >> 6, l = tid & 63;
    const float* xb = x + (size_t)b * 3 * NN;
    const float* yb = y + (size_t)b * 3 * NN;
    const float x0 = xb[n], x1 = xb[NN + n], x2 = xb[2 * NN + n];
    const float xs = x0 * x0 + x1 * x1 + x2 * x2;
    const int m0 = tid * 8;

    const float4 a0 = *(const float4*)(yb + m0);
    const float4 a1 = *(const float4*)(yb + m0 + 4);
    const float4 b0 = *(const float4*)(yb + NN + m0);
    const float4 b1 = *(const float4*)(yb + NN + m0 + 4);
    const float4 c0 = *(const float4*)(yb + 2 * NN + m0);
    const float4 c1 = *(const float4*)(yb + 2 * NN + m0 + 4);
    const float yy0[8] = {a0.x, a0.y, a0.z, a0.w, a1.x, a1.y, a1.z, a1.w};
    const float yy1[8] = {b0.x, b0.y, b0.z, b0.w, b1.x, b1.y, b1.z, b1.w};
    const float yy2[8] = {c0.x, c0.y, c0.z, c0.w, c1.x, c1.y, c1.z, c1.w};

    float k[8];
#pragma unroll
    for (int j = 0; j < 8; ++j) {
        const float ys  = yy0[j] * yy0[j] + yy1[j] * yy1[j] + yy2[j] * yy2[j];
        const float dot = x0 * yy0[j] + x1 * yy1[j] + x2 * yy2[j];
        const float C   = fmaxf(xs + ys - 2.0f * dot, 0.0f);
        k[j] = __expf(NEG_INV_EPS * C);
    }

    // row max -> pow2 scale
    float mx = fmaxf(fmaxf(fmaxf(k[0], k[1]), fmaxf(k[2], k[3])),
                     fmaxf(fmaxf(k[4], k[5]), fmaxf(k[6], k[7])));
#pragma unroll
    for (int off = 32; off > 0; off >>= 1) mx = fmaxf(mx, __shfl_xor(mx, off, 64));
    __shared__ float red[4];
    if (l == 0) red[w] = mx;
    __syncthreads();
    mx = fmaxf(fmaxf(red[0], red[1]), fmaxf(red[2], red[3]));
    mx = fmaxf(mx, 1e-30f);
    const int e = (int)((__float_as_uint(mx) >> 23) & 0xffu) - 127;   // mx in [2^e, 2^{e+1})
    const float sc = __uint_as_float((unsigned)(127 - e) << 23);      // scaled max in [1,2)
    if (tid == 0) INVS[b * NN + n] = __uint_as_float((unsigned)(127 + e) << 23);

    int p0 = __builtin_amdgcn_cvt_pk_fp8_f32(k[0] * sc, k[1] * sc, 0, false);
    p0     = __builtin_amdgcn_cvt_pk_fp8_f32(k[2] * sc, k[3] * sc, p0, true);
    int p1 = __builtin_amdgcn_cvt_pk_fp8_f32(k[4] * sc, k[5] * sc, 0, false);
    p1     = __builtin_amdgcn_cvt_pk_fp8_f32(k[6] * sc, k[7] * sc, p1, true);
    uint2 pk; pk.x = (unsigned)p0; pk.y = (unsigned)p1;
    *(uint2*)(K8 + ((size_t)(b * NN + n)) * NN + m0) = pk;
}

// ------------------------------------------------- reduce: v[m] = inv_n/(sum_g PART[g][m] + 1e-8)
__global__ __launch_bounds__(256) void reduce_v(const float* __restrict__ PART,
                                                float* __restrict__ VV) {
    const int t = blockIdx.x * 256 + threadIdx.x;         // t in [0, NB*NN/4)
    const int b = t >> 9;                                 // 512 float4 per batch
    const int m4 = (t & 511) << 2;
    const float* p = PART + (size_t)(b * G) * NN + m4;
    float s0 = 0, s1 = 0, s2 = 0, s3 = 0;
#pragma unroll 8
    for (int g = 0; g < G; ++g) {
        const float4 q = *(const float4*)(p + (size_t)g * NN);
        s0 += q.x; s1 += q.y; s2 += q.z; s3 += q.w;
    }
    float4 o;
    o.x = INV_N * fastrcp(s0 + 1e-8f);
    o.y = INV_N * fastrcp(s1 + 1e-8f);
    o.z = INV_N * fastrcp(s2 + 1e-8f);
    o.w = INV_N * fastrcp(s3 + 1e-8f);
    *(float4*)(VV + (size_t)b * NN + m4) = o;
}

// ------------------------------------------------- fused pass (single sweep of K8), round-5 structure
// + one-row-deep kv prefetch (2x in-flight bytes, +8 VGPR only).
// wave w owns rows g*32+w*8 .. +7; lane l owns cols {s*512 + l*8 + j}.
__global__ __launch_bounds__(256) void fused_pass(const unsigned char* __restrict__ K8,
                                                  const float* __restrict__ VV,
                                                  const float* __restrict__ INVS,
                                                  float* __restrict__ u_out,
                                                  float* __restrict__ PART,
                                                  int first) {
    const int g = blockIdx.x, b = blockIdx.y, tid = threadIdx.x;
    const int w = tid >> 6, l = tid & 63;

    float v[4][8];
    if (!first) {
        const float* vb = VV + b * NN;
#pragma unroll
        for (int s = 0; s < 4; ++s) {
            const float4 p0 = *(const float4*)(vb + s * 512 + l * 8);
            const float4 p1 = *(const float4*)(vb + s * 512 + l * 8 + 4);
            v[s][0] = p0.x; v[s][1] = p0.y; v[s][2] = p0.z; v[s][3] = p0.w;
            v[s][4] = p1.x; v[s][5] = p1.y; v[s][6] = p1.z; v[s][7] = p1.w;
        }
    }

    float acc[4][8];
#pragma unroll
    for (int s = 0; s < 4; ++s)
#pragma unroll
        for (int j = 0; j < 8; ++j) acc[s][j] = 0.0f;

    const int row0 = g * 32 + w * 8;
    const unsigned char* Kb = K8 + ((size_t)(b * NN + row0)) * NN + l * 8;
    const float* invp = INVS + b * NN + row0;

    uint2 kvC[4], kvN[4];
#pragma unroll
    for (int s = 0; s < 4; ++s) kvC[s] = *(const uint2*)(Kb + s * 512);

#pragma unroll
    for (int r = 0; r < 8; ++r) {
        // prefetch next row before the dependent dot/butterfly (r=7 reloads row0, L1-hot)
        const int rn = (r + 1) & 7;
#pragma unroll
        for (int s = 0; s < 4; ++s) kvN[s] = *(const uint2*)(Kb + (size_t)rn * NN + s * 512);

        const float invs = invp[r];
        float u;
        if (first) {
            u = INV_N;
        } else {
            float d0 = 0, d1 = 0, d2 = 0, d3 = 0, d4 = 0, d5 = 0, d6 = 0, d7 = 0;
#pragma unroll
            for (int s = 0; s < 4; ++s) {
                float f0, f1, f2, f3, f4, f5, f6, f7;
                dec4(kvC[s].x, f0, f1, f2, f3);
                dec4(kvC[s].y, f4, f5, f6, f7);
                d0 = fmaf(f0, v[s][0], d0); d1 = fmaf(f1, v[s][1], d1);
                d2 = fmaf(f2, v[s][2], d2); d3 = fmaf(f3, v[s][3], d3);
                d4 = fmaf(f4, v[s][4], d4); d5 = fmaf(f5, v[s][5], d5);
                d6 = fmaf(f6, v[s][6], d6); d7 = fmaf(f7, v[s][7], d7);
            }
            float d = ((d0 + d1) + (d2 + d3)) + ((d4 + d5) + (d6 + d7));
#pragma unroll
            for (int off = 32; off > 0; off >>= 1) d += __shfl_xor(d, off, 64);
            u = INV_N * fastrcp(d * invs + 1e-8f);
        }
        const float uw = u * invs;
        if (l == 0) u_out[b * NN + row0 + r] = uw;

#pragma unroll
        for (int s = 0; s < 4; ++s) {
            float f0, f1, f2, f3, f4, f5, f6, f7;
            dec4(kvC[s].x, f0, f1, f2, f3);
            dec4(kvC[s].y, f4, f5, f6, f7);
            acc[s][0] = fmaf(f0, uw, acc[s][0]); acc[s][1] = fmaf(f1, uw, acc[s][1]);
            acc[s][2] = fmaf(f2, uw, acc[s][2]); acc[s][3] = fmaf(f3, uw, acc[s][3]);
            acc[s][4] = fmaf(f4, uw, acc[s][4]); acc[s][5] = fmaf(f5, uw, acc[s][5]);
            acc[s][6] = fmaf(f6, uw, acc[s][6]); acc[s][7] = fmaf(f7, uw, acc[s][7]);
        }
#pragma unroll
        for (int s = 0; s < 4; ++s) kvC[s] = kvN[s];
    }

    // fold 4 waves' column partials via LDS, one store per block
    __shared__ float lds[4][NN];                            // 32 KB
#pragma unroll
    for (int s = 0; s < 4; ++s) {
        *(float4*)&lds[w][s * 512 + l * 8]     = make_float4(acc[s][0], acc[s][1], acc[s][2], acc[s][3]);
        *(float4*)&lds[w][s * 512 + l * 8 + 4] = make_float4(acc[s][4], acc[s][5], acc[s][6], acc[s][7]);
    }
    __syncthreads();
    float o[8];
#pragma unroll
    for (int j = 0; j < 8; ++j)
        o[j] = (lds[0][tid * 8 + j] + lds[1][tid * 8 + j]) +
               (lds[2][tid * 8 + j] + lds[3][tid * 8 + j]);
    float* p = PART + ((size_t)(b * G + g)) * NN + tid * 8;
    *(float4*)(p)     = make_float4(o[0], o[1], o[2], o[3]);
    *(float4*)(p + 4) = make_float4(o[4], o[5], o[6], o[7]);
}

// ------------------------------------------------- final: sum uw[n]*K8[n,m]*C[n,m]*v[m] / B
__global__ __launch_bounds__(256) void final_sum(const unsigned char* __restrict__ K8,
                                                 const float* __restrict__ x,
                                                 const float* __restrict__ y,
                                                 const float* __restrict__ VV,
                                                 const float* __restrict__ u_in,   // holds uw = u*invs
                                                 float* __restrict__ out) {
    const int g = blockIdx.x, b = blockIdx.y, tid = threadIdx.x;
    const int w = tid >> 6, l = tid & 63;
    const float* vb = VV + b * NN;

    float v[4][8];
#pragma unroll
    for (int s = 0; s < 4; ++s) {
        const float4 p0 = *(const float4*)(vb + s * 512 + l * 8);
        const float4 p1 = *(const float4*)(vb + s * 512 + l * 8 + 4);
        v[s][0] = p0.x; v[s][1] = p0.y; v[s][2] = p0.z; v[s][3] = p0.w;
        v[s][4] = p1.x; v[s][5] = p1.y; v[s][6] = p1.z; v[s][7] = p1.w;
    }

    const float* xb = x + (size_t)b * 3 * NN;
    const float* yb = y + (size_t)b * 3 * NN;
    float lacc = 0.0f;

    for (int r = 0; r < 8; ++r) {
        const int n = g * 32 + w * 8 + r;
        const float x0 = xb[n], x1 = xb[NN + n], x2 = xb[2 * NN + n];
        const float xs = x0 * x0 + x1 * x1 + x2 * x2;
        const float uwn = u_in[b * NN + n];
        const unsigned char* Kp = K8 + ((size_t)(b * NN + n)) * NN + l * 8;
        float racc = 0.0f;
#pragma unroll
        for (int s = 0; s < 4; ++s) {
            const int m0 = s * 512 + l * 8;
            const uint2 kv = *(const uint2*)(Kp + s * 512);
            float ky[8];
            dec4(kv.x, ky[0], ky[1], ky[2], ky[3]);
            dec4(kv.y, ky[4], ky[5], ky[6], ky[7]);
            const float4 a0 = *(const float4*)(yb + m0);
            const float4 a1 = *(const float4*)(yb + m0 + 4);
            const float4 b0 = *(const float4*)(yb + NN + m0);
            const float4 b1 = *(const float4*)(yb + NN + m0 + 4);
            const float4 c0 = *(const float4*)(yb + 2 * NN + m0);
            const float4 c1 = *(const float4*)(yb + 2 * NN + m0 + 4);
            const float yy0[8] = {a0.x, a0.y, a0.z, a0.w, a1.x, a1.y, a1.z, a1.w};
            const float yy1[8] = {b0.x, b0.y, b0.z, b0.w, b1.x, b1.y, b1.z, b1.w};
            const float yy2[8] = {c0.x, c0.y, c0.z, c0.w, c1.x, c1.y, c1.z, c1.w};
#pragma unroll
            for (int j = 0; j < 8; ++j) {
                const float ys  = yy0[j] * yy0[j] + yy1[j] * yy1[j] + yy2[j] * yy2[j];
                const float dot = x0 * yy0[j] + x1 * yy1[j] + x2 * yy2[j];
                const float C   = fmaxf(xs + ys - 2.0f * dot, 0.0f);
                racc = fmaf(ky[j] * C, v[s][j], racc);
            }
        }
        lacc = fmaf(uwn, racc, lacc);   // uwn uniform per row: defer lane-reduction
    }
#pragma unroll
    for (int off = 32; off > 0; off >>= 1) lacc += __shfl_xor(lacc, off, 64);
    __shared__ float red[4];
    if (l == 0) red[w] = lacc;
    __syncthreads();
    if (tid == 0) atomicAdd(out, (red[0] + red[1] + red[2] + red[3]) * (1.0f / (float)NB));
}

extern "C" void kernel_launch(void* const* d_in, const int* in_sizes, int n_in,
                              void* d_out, int out_size, void* d_ws, size_t ws_size,
                              hipStream_t stream) {
    const float* x = (const float*)d_in[0];
    const float* y = (const float*)d_in[1];
    float* out = (float*)d_out;
    char* ws = (char*)d_ws;

    unsigned char* K8 = (unsigned char*)ws;                  // 16*2048*2048 = 67,108,864 B
    const size_t KBYTES = (size_t)NB * NN * NN;
    float* PART = (float*)(ws + KBYTES);                     // 16*64*2048*4 = 8 MiB
    const size_t PARTN = (size_t)NB * G * NN;
    float* VV   = PART + PARTN;                              // v vector, 128 KiB
    float* ub   = VV + (size_t)NB * NN;                      // uw vector, 128 KiB
    float* INVS = ub + (size_t)NB * NN;                      // per-row 1/scale, 128 KiB

    hipMemsetAsync(out, 0, sizeof(float), stream);

    build_K<<<dim3(NN, NB), 256, 0, stream>>>(x, y, K8, INVS);

    // iteration 0 half-step: PART <- K^T u0 (u0 = inv_n), phase A skipped
    fused_pass<<<dim3(G, NB), 256, 0, stream>>>(K8, VV, INVS, ub, PART, 1);
    for (int i = 0; i < ITERS; ++i) {
        reduce_v<<<dim3(NB * NN / 4 / 256), 256, 0, stream>>>(PART, VV);           // v_k
        fused_pass<<<dim3(G, NB), 256, 0, stream>>>(K8, VV, INVS, ub, PART, 0);    // u_k, PART
    }
    // ub = uw_100, VV = v_100
    final_sum<<<dim3(G, NB), 256, 0, stream>>>(K8, x, y, VV, ub, out);
}

// Round 9
// 2740.147 us; speedup vs baseline: 1.1710x; 1.1710x over previous
//
#include <hip/hip_runtime.h>

#define NB 16
#define NN 2048
#define G  128                // blocks per batch; block owns 16 rows (4 waves x 4 rows)
#define RPB 16                // rows per block
#define RPW 4                 // rows per wave
#define ITERS 100

typedef float v2f __attribute__((ext_vector_type(2)));

static constexpr float INV_N = 1.0f / (float)NN;
static constexpr float NEG_INV_EPS = -10.0f;     // -1/eps, eps = 0.1

__device__ __forceinline__ float fastrcp(float x) { return __builtin_amdgcn_rcpf(x); }

// decode 4 packed fp8-e4m3 bytes -> 4 floats (HW v_cvt_pk_f32_fp8)
__device__ __forceinline__ void dec4(unsigned int u, float& f0, float& f1, float& f2, float& f3) {
    v2f lo = __builtin_amdgcn_cvt_pk_f32_fp8((int)u, false);
    v2f hi = __builtin_amdgcn_cvt_pk_f32_fp8((int)u, true);
    f0 = lo[0]; f1 = lo[1]; f2 = hi[0]; f3 = hi[1];
}

// ------------------------------------------------- build K8 = fp8(K * s_row), INVS = 1/s_row (pow2)
__global__ __launch_bounds__(256) void build_K(const float* __restrict__ x,
                                               const float* __restrict__ y,
                                               unsigned char* __restrict__ K8,
                                               float* __restrict__ INVS) {
    const int n = blockIdx.x, b = blockIdx.y, tid = threadIdx.x;
    const int w = tid >> 6, l = tid & 63;
    const float* xb = x + (size_t)b * 3 * NN;
    const float* yb = y + (size_t)b * 3 * NN;
    const float x0 = xb[n], x1 = xb[NN + n], x2 = xb[2 * NN + n];
    const float xs = x0 * x0 + x1 * x1 + x2 * x2;
    const int m0 = tid * 8;

    const float4 a0 = *(const float4*)(yb + m0);
    const float4 a1 = *(const float4*)(yb + m0 + 4);
    const float4 b0 = *(const float4*)(yb + NN + m0);
    const float4 b1 = *(const float4*)(yb + NN + m0 + 4);
    const float4 c0 = *(const float4*)(yb + 2 * NN + m0);
    const float4 c1 = *(const float4*)(yb + 2 * NN + m0 + 4);
    const float yy0[8] = {a0.x, a0.y, a0.z, a0.w, a1.x, a1.y, a1.z, a1.w};
    const float yy1[8] = {b0.x, b0.y, b0.z, b0.w, b1.x, b1.y, b1.z, b1.w};
    const float yy2[8] = {c0.x, c0.y, c0.z, c0.w, c1.x, c1.y, c1.z, c1.w};

    float k[8];
#pragma unroll
    for (int j = 0; j < 8; ++j) {
        const float ys  = yy0[j] * yy0[j] + yy1[j] * yy1[j] + yy2[j] * yy2[j];
        const float dot = x0 * yy0[j] + x1 * yy1[j] + x2 * yy2[j];
        const float C   = fmaxf(xs + ys - 2.0f * dot, 0.0f);
        k[j] = __expf(NEG_INV_EPS * C);
    }

    // row max -> pow2 scale
    float mx = fmaxf(fmaxf(fmaxf(k[0], k[1]), fmaxf(k[2], k[3])),
                     fmaxf(fmaxf(k[4], k[5]), fmaxf(k[6], k[7])));
#pragma unroll
    for (int off = 32; off > 0; off >>= 1) mx = fmaxf(mx, __shfl_xor(mx, off, 64));
    __shared__ float red[4];
    if (l == 0) red[w] = mx;
    __syncthreads();
    mx = fmaxf(fmaxf(red[0], red[1]), fmaxf(red[2], red[3]));
    mx = fmaxf(mx, 1e-30f);
    const int e = (int)((__float_as_uint(mx) >> 23) & 0xffu) - 127;   // mx in [2^e, 2^{e+1})
    const float sc = __uint_as_float((unsigned)(127 - e) << 23);      // scaled max in [1,2)
    if (tid == 0) INVS[b * NN + n] = __uint_as_float((unsigned)(127 + e) << 23);

    int p0 = __builtin_amdgcn_cvt_pk_fp8_f32(k[0] * sc, k[1] * sc, 0, false);
    p0     = __builtin_amdgcn_cvt_pk_fp8_f32(k[2] * sc, k[3] * sc, p0, true);
    int p1 = __builtin_amdgcn_cvt_pk_fp8_f32(k[4] * sc, k[5] * sc, 0, false);
    p1     = __builtin_amdgcn_cvt_pk_fp8_f32(k[6] * sc, k[7] * sc, p1, true);
    uint2 pk; pk.x = (unsigned)p0; pk.y = (unsigned)p1;
    *(uint2*)(K8 + ((size_t)(b * NN + n)) * NN + m0) = pk;
}

// ------------------------------------------------- reduce: v[m] = inv_n/(sum_g PART[g][m] + 1e-8)
// thread-per-column (coalesced 4B across lanes), 128 blocks to spread across CUs
__global__ __launch_bounds__(256) void reduce_v(const float* __restrict__ PART,
                                                float* __restrict__ VV) {
    const int t = blockIdx.x * 256 + threadIdx.x;         // t in [0, NB*NN)
    const int b = t >> 11, m = t & (NN - 1);
    const float* p = PART + (size_t)(b * G) * NN + m;
    float s = 0.0f;
#pragma unroll 16
    for (int g = 0; g < G; ++g) s += p[(size_t)g * NN];
    VV[t] = INV_N * fastrcp(s + 1e-8f);
}

// ------------------------------------------------- fused pass (single sweep of K8), round-5 inner loop
// wave w owns rows g*16+w*4 .. +3; lane l owns cols {s*512 + l*8 + j}.
__global__ __launch_bounds__(256) void fused_pass(const unsigned char* __restrict__ K8,
                                                  const float* __restrict__ VV,
                                                  const float* __restrict__ INVS,
                                                  float* __restrict__ u_out,
                                                  float* __restrict__ PART,
                                                  int first) {
    const int g = blockIdx.x, b = blockIdx.y, tid = threadIdx.x;
    const int w = tid >> 6, l = tid & 63;

    float v[4][8];
    if (!first) {
        const float* vb = VV + b * NN;
#pragma unroll
        for (int s = 0; s < 4; ++s) {
            const float4 p0 = *(const float4*)(vb + s * 512 + l * 8);
            const float4 p1 = *(const float4*)(vb + s * 512 + l * 8 + 4);
            v[s][0] = p0.x; v[s][1] = p0.y; v[s][2] = p0.z; v[s][3] = p0.w;
            v[s][4] = p1.x; v[s][5] = p1.y; v[s][6] = p1.z; v[s][7] = p1.w;
        }
    }

    float acc[4][8];
#pragma unroll
    for (int s = 0; s < 4; ++s)
#pragma unroll
        for (int j = 0; j < 8; ++j) acc[s][j] = 0.0f;

    const int row0 = g * RPB + w * RPW;
    const unsigned char* Kb = K8 + ((size_t)(b * NN + row0)) * NN + l * 8;
    const float* invp = INVS + b * NN + row0;

#pragma unroll 2
    for (int r = 0; r < RPW; ++r) {
        uint2 kv[4];
#pragma unroll
        for (int s = 0; s < 4; ++s) kv[s] = *(const uint2*)(Kb + (size_t)r * NN + s * 512);
        const float invs = invp[r];

        float u;
        if (first) {
            u = INV_N;
        } else {
            float d0 = 0, d1 = 0, d2 = 0, d3 = 0, d4 = 0, d5 = 0, d6 = 0, d7 = 0;
#pragma unroll
            for (int s = 0; s < 4; ++s) {
                float f0, f1, f2, f3, f4, f5, f6, f7;
                dec4(kv[s].x, f0, f1, f2, f3);
                dec4(kv[s].y, f4, f5, f6, f7);
                d0 = fmaf(f0, v[s][0], d0); d1 = fmaf(f1, v[s][1], d1);
                d2 = fmaf(f2, v[s][2], d2); d3 = fmaf(f3, v[s][3], d3);
                d4 = fmaf(f4, v[s][4], d4); d5 = fmaf(f5, v[s][5], d5);
                d6 = fmaf(f6, v[s][6], d6); d7 = fmaf(f7, v[s][7], d7);
            }
            float d = ((d0 + d1) + (d2 + d3)) + ((d4 + d5) + (d6 + d7));
#pragma unroll
            for (int off = 32; off > 0; off >>= 1) d += __shfl_xor(d, off, 64);
            u = INV_N * fastrcp(d * invs + 1e-8f);
        }
        const float uw = u * invs;
        if (l == 0) u_out[b * NN + row0 + r] = uw;

#pragma unroll
        for (int s = 0; s < 4; ++s) {
            float f0, f1, f2, f3, f4, f5, f6, f7;
            dec4(kv[s].x, f0, f1, f2, f3);
            dec4(kv[s].y, f4, f5, f6, f7);
            acc[s][0] = fmaf(f0, uw, acc[s][0]); acc[s][1] = fmaf(f1, uw, acc[s][1]);
            acc[s][2] = fmaf(f2, uw, acc[s][2]); acc[s][3] = fmaf(f3, uw, acc[s][3]);
            acc[s][4] = fmaf(f4, uw, acc[s][4]); acc[s][5] = fmaf(f5, uw, acc[s][5]);
            acc[s][6] = fmaf(f6, uw, acc[s][6]); acc[s][7] = fmaf(f7, uw, acc[s][7]);
        }
    }

    // fold 4 waves' column partials via LDS, one store per block
    __shared__ float lds[4][NN];                            // 32 KB
#pragma unroll
    for (int s = 0; s < 4; ++s) {
        *(float4*)&lds[w][s * 512 + l * 8]     = make_float4(acc[s][0], acc[s][1], acc[s][2], acc[s][3]);
        *(float4*)&lds[w][s * 512 + l * 8 + 4] = make_float4(acc[s][4], acc[s][5], acc[s][6], acc[s][7]);
    }
    __syncthreads();
    float o[8];
#pragma unroll
    for (int j = 0; j < 8; ++j)
        o[j] = (lds[0][tid * 8 + j] + lds[1][tid * 8 + j]) +
               (lds[2][tid * 8 + j] + lds[3][tid * 8 + j]);
    float* p = PART + ((size_t)(b * G + g)) * NN + tid * 8;
    *(float4*)(p)     = make_float4(o[0], o[1], o[2], o[3]);
    *(float4*)(p + 4) = make_float4(o[4], o[5], o[6], o[7]);
}

// ------------------------------------------------- final: sum uw[n]*K8[n,m]*C[n,m]*v[m] / B
__global__ __launch_bounds__(256) void final_sum(const unsigned char* __restrict__ K8,
                                                 const float* __restrict__ x,
                                                 const float* __restrict__ y,
                                                 const float* __restrict__ VV,
                                                 const float* __restrict__ u_in,   // holds uw = u*invs
                                                 float* __restrict__ out) {
    const int g = blockIdx.x, b = blockIdx.y, tid = threadIdx.x;
    const int w = tid >> 6, l = tid & 63;
    const float* vb = VV + b * NN;

    float v[4][8];
#pragma unroll
    for (int s = 0; s < 4; ++s) {
        const float4 p0 = *(const float4*)(vb + s * 512 + l * 8);
        const float4 p1 = *(const float4*)(vb + s * 512 + l * 8 + 4);
        v[s][0] = p0.x; v[s][1] = p0.y; v[s][2] = p0.z; v[s][3] = p0.w;
        v[s][4] = p1.x; v[s][5] = p1.y; v[s][6] = p1.z; v[s][7] = p1.w;
    }

    const float* xb = x + (size_t)b * 3 * NN;
    const float* yb = y + (size_t)b * 3 * NN;
    float lacc = 0.0f;

    for (int r = 0; r < RPW; ++r) {
        const int n = g * RPB + w * RPW + r;
        const float x0 = xb[n], x1 = xb[NN + n], x2 = xb[2 * NN + n];
        const float xs = x0 * x0 + x1 * x1 + x2 * x2;
        const float uwn = u_in[b * NN + n];
        const unsigned char* Kp = K8 + ((size_t)(b * NN + n)) * NN + l * 8;
        float racc = 0.0f;
#pragma unroll
        for (int s = 0; s < 4; ++s) {
            const int m0 = s * 512 + l * 8;
            const uint2 kv = *(const uint2*)(Kp + s * 512);
            float ky[8];
            dec4(kv.x, ky[0], ky[1], ky[2], ky[3]);
            dec4(kv.y, ky[4], ky[5], ky[6], ky[7]);
            const float4 a0 = *(const float4*)(yb + m0);
            const float4 a1 = *(const float4*)(yb + m0 + 4);
            const float4 b0 = *(const float4*)(yb + NN + m0);
            const float4 b1 = *(const float4*)(yb + NN + m0 + 4);
            const float4 c0 = *(const float4*)(yb + 2 * NN + m0);
            const float4 c1 = *(const float4*)(yb + 2 * NN + m0 + 4);
            const float yy0[8] = {a0.x, a0.y, a0.z, a0.w, a1.x, a1.y, a1.z, a1.w};
            const float yy1[8] = {b0.x, b0.y, b0.z, b0.w, b1.x, b1.y, b1.z, b1.w};
            const float yy2[8] = {c0.x, c0.y, c0.z, c0.w, c1.x, c1.y, c1.z, c1.w};
#pragma unroll
            for (int j = 0; j < 8; ++j) {
                const float ys  = yy0[j] * yy0[j] + yy1[j] * yy1[j] + yy2[j] * yy2[j];
                const float dot = x0 * yy0[j] + x1 * yy1[j] + x2 * yy2[j];
                const float C   = fmaxf(xs + ys - 2.0f * dot, 0.0f);
                racc = fmaf(ky[j] * C, v[s][j], racc);
            }
        }
        lacc = fmaf(uwn, racc, lacc);   // uwn uniform per row: defer lane-reduction
    }
#pragma unroll
    for (int off = 32; off > 0; off >>= 1) lacc += __shfl_xor(lacc, off, 64);
    __shared__ float red[4];
    if (l == 0) red[w] = lacc;
    __syncthreads();
    if (tid == 0) atomicAdd(out, (red[0] + red[1] + red[2] + red[3]) * (1.0f / (float)NB));
}

extern "C" void kernel_launch(void* const* d_in, const int* in_sizes, int n_in,
                              void* d_out, int out_size, void* d_ws, size_t ws_size,
                              hipStream_t stream) {
    const float* x = (const float*)d_in[0];
    const float* y = (const float*)d_in[1];
    float* out = (float*)d_out;
    char* ws = (char*)d_ws;

    unsigned char* K8 = (unsigned char*)ws;                  // 16*2048*2048 = 67,108,864 B
    const size_t KBYTES = (size_t)NB * NN * NN;
    float* PART = (float*)(ws + KBYTES);                     // 16*128*2048*4 = 16 MiB
    const size_t PARTN = (size_t)NB * G * NN;
    float* VV   = PART + PARTN;                              // v vector, 128 KiB
    float* ub   = VV + (size_t)NB * NN;                      // uw vector, 128 KiB
    float* INVS = ub + (size_t)NB * NN;                      // per-row 1/scale, 128 KiB

    hipMemsetAsync(out, 0, sizeof(float), stream);

    build_K<<<dim3(NN, NB), 256, 0, stream>>>(x, y, K8, INVS);

    // iteration 0 half-step: PART <- K^T u0 (u0 = inv_n), phase A skipped
    fused_pass<<<dim3(G, NB), 256, 0, stream>>>(K8, VV, INVS, ub, PART, 1);
    for (int i = 0; i < ITERS; ++i) {
        reduce_v<<<dim3(NB * NN / 256), 256, 0, stream>>>(PART, VV);               // v_k
        fused_pass<<<dim3(G, NB), 256, 0, stream>>>(K8, VV, INVS, ub, PART, 0);    // u_k, PART
    }
    // ub = uw_100, VV = v_100
    final_sum<<<dim3(G, NB), 256, 0, stream>>>(K8, x, y, VV, ub, out);
}